// Round 8
// baseline (428.877 us; speedup 1.0000x reference)
//
#include <hip/hip_runtime.h>

// CRF NLL forward loss. B=256, T=2048, K2=52 (50 labels + START=50 + STOP=51).
// Bidirectional linear-domain recurrence with fwd/bwd as SEPARATE single-wave
// workgroups (R7 lesson: 2 waves in one workgroup co-scheduled badly; per-step
// 706 cyc vs 454 single-wave).
//   fwd : v <- E_t * (M v),        t = 0..h-1,          v0 = e_START
//   bwd : w <- E_t * (M^T w),      t = L-2 down to h,   w init = E_{L-1} * s
//   score = ln2*(Cf + Cb + log2(w^T M v))   [combine kernel does the extra matvec]
// Same step macro for both roles (matvec then elementwise mul at end).
// Renorm by a fixed positive lane every 4 steps (R5-proven, absmax 0.0).

#define B_    256
#define T_    2048
#define K2_   52
#define LOG2E_ 1.4426950408889634f
#define LN2_   0.6931471805599453f

__device__ __forceinline__ float rdlane(float v, int src) {
  return __uint_as_float(__builtin_amdgcn_readlane(__float_as_uint(v), src));
}
__device__ __forceinline__ int imin(int a, int b) { return a < b ? a : b; }
__device__ __forceinline__ int imax(int a, int b) { return a > b ? a : b; }

// F(i, c): i = prev-state index, c = accumulator chain (i % 4)
#define FORALL52(F) \
  F(0,0) F(1,1) F(2,2) F(3,3) F(4,0) F(5,1) F(6,2) F(7,3) \
  F(8,0) F(9,1) F(10,2) F(11,3) F(12,0) F(13,1) F(14,2) F(15,3) \
  F(16,0) F(17,1) F(18,2) F(19,3) F(20,0) F(21,1) F(22,2) F(23,3) \
  F(24,0) F(25,1) F(26,2) F(27,3) F(28,0) F(29,1) F(30,2) F(31,3) \
  F(32,0) F(33,1) F(34,2) F(35,3) F(36,0) F(37,1) F(38,2) F(39,3) \
  F(40,0) F(41,1) F(42,2) F(43,3) F(48,0) F(49,1) F(50,2) F(51,3) \
  F(44,0) F(45,1) F(46,2) F(47,3)

#define DECLM_F(i, c) float M_##i = __builtin_amdgcn_exp2f(tr[n * K2_ + i] * LOG2E_);
#define DECLM_B(i, c) float M_##i = __builtin_amdgcn_exp2f(tr[i * K2_ + n] * LOG2E_);
#define ACCF(i, c)  _a##c = fmaf(M_##i, rdlane(_src, i), _a##c);

#define MATVEC(OUTY) \
    float _a0 = 0.0f, _a1 = 0.0f, _a2 = 0.0f, _a3 = 0.0f; \
    FORALL52(ACCF) \
    float OUTY = (_a0 + _a1) + (_a2 + _a3);

// step: vv <- E * (M vv); renorm reference lane RL (must be >0) on _R variant
#define STEP_R(EV, NEWIDX, RL) do {                             \
    float _ne  = emb[(NEWIDX) * K2_ + n];                       \
    float _m   = rdlane(vv, RL);                                \
    float _inv = __builtin_amdgcn_rcpf(_m);                     \
    C += __builtin_amdgcn_logf(_m);        /* v_log_f32 = log2 */ \
    float _E = __builtin_amdgcn_exp2f((EV) * LOG2E_);           \
    float _src = vv;                                            \
    MATVEC(_y)                                                  \
    vv = _y * _inv * _E;                                        \
    EV = _ne;                                                   \
  } while (0)
#define STEP_N(EV, NEWIDX) do {                                 \
    float _ne  = emb[(NEWIDX) * K2_ + n];                       \
    float _E = __builtin_amdgcn_exp2f((EV) * LOG2E_);           \
    float _src = vv;                                            \
    MATVEC(_y)                                                  \
    vv = _y * _E;                                               \
    EV = _ne;                                                   \
  } while (0)

#define PIN(a,b,c,d,e,f,g,h,i,j,k,l,m) \
  asm volatile("" : "+v"(M_##a), "+v"(M_##b), "+v"(M_##c), "+v"(M_##d), \
                    "+v"(M_##e), "+v"(M_##f), "+v"(M_##g), "+v"(M_##h), \
                    "+v"(M_##i), "+v"(M_##j), "+v"(M_##k), "+v"(M_##l), \
                    "+v"(M_##m));
#define PIN_ALL \
  PIN( 0, 1, 2, 3, 4, 5, 6, 7, 8, 9,10,11,12) \
  PIN(13,14,15,16,17,18,19,20,21,22,23,24,25) \
  PIN(26,27,28,29,30,31,32,33,34,35,36,37,38) \
  PIN(39,40,41,42,43,44,45,46,47,48,49,50,51)

// d_ws float layout:
//   [0, 13312)            v per batch (52 each)
//   [13312, 26624)        w per batch (52 each)
//   [26624, 27136)        C per batch*2 (Cf, Cb)
//   [27136, 27392)        per-batch scores
#define WSV 0
#define WSW (B_ * K2_)
#define WSC (2 * B_ * K2_)
#define WSS (2 * B_ * K2_ + 2 * B_)

__launch_bounds__(64, 1)
__global__ void crf_chain_kernel(const float* __restrict__ em,
                                 const float* __restrict__ tr,
                                 const int*  __restrict__ len,
                                 float* __restrict__ ws)
{
  const int role = blockIdx.x & 1;               // 0 = fwd, 1 = bwd
  const int b    = blockIdx.x >> 1;
  const int lane = threadIdx.x;                  // 64
  const int n    = (lane < K2_) ? lane : (K2_ - 1);
  const int L    = len[b];
  const int h    = L >> 1;
  const float* emb = em + (size_t)b * (T_ * K2_);

  float vv, C = 0.0f;

  if (role == 0) {
    // ---------- forward: h steps over rows 0..h-1 ----------
    FORALL52(DECLM_F)
    PIN_ALL
    vv = (lane == 50) ? 1.0f : 0.0f;
    float e0 = emb[0 * K2_ + n];
    float e1 = emb[1 * K2_ + n];
    float e2 = emb[2 * K2_ + n];
    float e3 = emb[3 * K2_ + n];
    int t = 0;
    for (; t + 4 <= h; t += 4) {
      int i4 = imin(t + 4, T_ - 1), i5 = imin(t + 5, T_ - 1);
      int i6 = imin(t + 6, T_ - 1), i7 = imin(t + 7, T_ - 1);
      STEP_R(e0, i4, 50);
      STEP_N(e1, i5);
      STEP_N(e2, i6);
      STEP_N(e3, i7);
    }
    int rem = h - t;
    if (rem > 0) STEP_R(e0, T_ - 1, 50);
    if (rem > 1) STEP_N(e1, T_ - 1);
    if (rem > 2) STEP_N(e2, T_ - 1);
    if (lane < K2_) ws[WSV + b * K2_ + lane] = vv;
  } else {
    // ---------- backward (w-form): init from row L-1, then L-1-h steps over
    // rows L-2 down to h, identical step shape with M^T ----------
    FORALL52(DECLM_B)
    PIN_ALL
    vv = __builtin_amdgcn_exp2f((emb[(L - 1) * K2_ + n] + tr[(K2_ - 1) * K2_ + n]) * LOG2E_);
    const int cnt = L - 1 - h;
    float e0 = emb[imax(L - 2, 0) * K2_ + n];
    float e1 = emb[imax(L - 3, 0) * K2_ + n];
    float e2 = emb[imax(L - 4, 0) * K2_ + n];
    float e3 = emb[imax(L - 5, 0) * K2_ + n];
    int s = 0;
    for (; s + 4 <= cnt; s += 4) {
      int j4 = imax(L - 6 - s, 0), j5 = imax(L - 7 - s, 0);
      int j6 = imax(L - 8 - s, 0), j7 = imax(L - 9 - s, 0);
      STEP_R(e0, j4, 0);
      STEP_N(e1, j5);
      STEP_N(e2, j6);
      STEP_N(e3, j7);
    }
    int rem = cnt - s;
    if (rem > 0) STEP_R(e0, 0, 0);
    if (rem > 1) STEP_N(e1, 0);
    if (rem > 2) STEP_N(e2, 0);
    if (lane < K2_) ws[WSW + b * K2_ + lane] = vv;
  }
  if (lane == 0) ws[WSC + b * 2 + role] = C;
}

// Per-batch combine: score = ln2*(Cf+Cb+log2(w . (M v))) - gold
__launch_bounds__(64, 1)
__global__ void crf_combine_kernel(const float* __restrict__ em,
                                   const float* __restrict__ tr,
                                   const int*  __restrict__ len,
                                   const int*  __restrict__ lab,
                                   float* __restrict__ ws)
{
  const int b    = blockIdx.x;
  const int lane = threadIdx.x;
  const int n    = (lane < K2_) ? lane : (K2_ - 1);
  const int L    = len[b];
  const float* emb = em + (size_t)b * (T_ * K2_);

  FORALL52(DECLM_F)
  float vv = (lane < K2_) ? ws[WSV + b * K2_ + lane] : 0.0f;
  float _src = vv;
  MATVEC(_z)
  float w = (lane < K2_) ? ws[WSW + b * K2_ + lane] : 0.0f;
  float x = w * _z;
#pragma unroll
  for (int off = 32; off >= 1; off >>= 1)
    x += __shfl_xor(x, off, 64);
  float fwd = (ws[WSC + b * 2] + ws[WSC + b * 2 + 1] + __builtin_amdgcn_logf(x)) * LN2_;

  float gold = 0.0f;
  const int* labb = lab + b * T_;
  for (int t = lane; t < L; t += 64) {
    int l1 = labb[t];
    int l0 = (t == 0) ? 50 : labb[t - 1];
    gold += emb[t * K2_ + l1] + tr[l1 * K2_ + l0];
  }
  if (lane == 0) gold += tr[(K2_ - 1) * K2_ + labb[L - 1]];  // STOP <- last label
#pragma unroll
  for (int off = 32; off >= 1; off >>= 1)
    gold += __shfl_xor(gold, off, 64);

  if (lane == 0) ws[WSS + b] = fwd - gold;
}

__global__ void reduce_mean_kernel(const float* __restrict__ ws,
                                   float* __restrict__ out)
{
  const int tid = threadIdx.x;  // 256
  float v = ws[WSS + tid];
#pragma unroll
  for (int off = 32; off >= 1; off >>= 1) v += __shfl_xor(v, off, 64);
  __shared__ float s[4];
  if ((tid & 63) == 0) s[tid >> 6] = v;
  __syncthreads();
  if (tid == 0) out[0] = ((s[0] + s[1]) + (s[2] + s[3])) * (1.0f / (float)B_);
}

extern "C" void kernel_launch(void* const* d_in, const int* in_sizes, int n_in,
                              void* d_out, int out_size, void* d_ws, size_t ws_size,
                              hipStream_t stream) {
  const float* em  = (const float*)d_in[0];   // [B,T,K2] f32
  const float* tr  = (const float*)d_in[1];   // [K2,K2]  f32
  const int*   len = (const int*)d_in[2];     // [B] i32
  const int*   lab = (const int*)d_in[3];     // [B,T] i32
  float* out = (float*)d_out;
  float* ws  = (float*)d_ws;                  // needs (2*256*52 + 2*256 + 256)*4 B ~ 110 KB

  crf_chain_kernel<<<2 * B_, 64, 0, stream>>>(em, tr, len, ws);
  crf_combine_kernel<<<B_, 64, 0, stream>>>(em, tr, len, lab, ws);
  reduce_mean_kernel<<<1, 256, 0, stream>>>(ws, out);
}